// Round 1
// baseline (22328.720 us; speedup 1.0000x reference)
//
#include <hip/hip_runtime.h>
#include <hip/hip_bf16.h>

#define T_STEPS 512
#define BATCH   64
#define IN_DIM  1024
#define HID     1024

// ---------------------------------------------------------------------------
// Kernel A: xp[m][n] = sum_k input[m][k]*W_ih[n][k] + b_ih[n] + b_hh[n]
// M = T*B = 32768, N = H = 1024, K = I = 1024. fp32 vector GEMM.
// BM=128, BN=64, BK=32, 256 threads, 8x4 micro-tile per thread.
// Writes into d_out[0 : T*B*H] (consumed in-place by the recurrent kernel).
// ---------------------------------------------------------------------------
__global__ __launch_bounds__(256) void xproj_kernel(
    const float* __restrict__ A,     // [M][K] input
    const float* __restrict__ W,     // [N][K] W_ih
    const float* __restrict__ b_ih,  // [N]
    const float* __restrict__ b_hh,  // [N]
    float* __restrict__ out)         // [M][N]
{
    constexpr int BM = 128, BN = 64, BK = 32;
    __shared__ float As[BK][BM + 4];   // k-major, padded
    __shared__ float Bs[BK][BN + 4];

    const int n0 = blockIdx.x * BN;
    const int m0 = blockIdx.y * BM;
    const int tid = threadIdx.x;
    const int tx = tid & 15;        // n direction (4 cols each)
    const int ty = tid >> 4;        // m direction (8 rows each)

    float acc[8][4] = {};

    for (int k0 = 0; k0 < IN_DIM; k0 += BK) {
        // stage A tile: 128 rows x 32 k = 1024 float4, 4 per thread
        #pragma unroll
        for (int i = 0; i < 4; i++) {
            int f4 = i * 256 + tid;
            int r = f4 >> 3, c4 = f4 & 7;
            float4 v = *(const float4*)(A + (long)(m0 + r) * IN_DIM + k0 + c4 * 4);
            As[c4 * 4 + 0][r] = v.x;
            As[c4 * 4 + 1][r] = v.y;
            As[c4 * 4 + 2][r] = v.z;
            As[c4 * 4 + 3][r] = v.w;
        }
        // stage W tile: 64 rows x 32 k = 512 float4, 2 per thread
        #pragma unroll
        for (int i = 0; i < 2; i++) {
            int f4 = i * 256 + tid;
            int r = f4 >> 3, c4 = f4 & 7;
            float4 v = *(const float4*)(W + (long)(n0 + r) * IN_DIM + k0 + c4 * 4);
            Bs[c4 * 4 + 0][r] = v.x;
            Bs[c4 * 4 + 1][r] = v.y;
            Bs[c4 * 4 + 2][r] = v.z;
            Bs[c4 * 4 + 3][r] = v.w;
        }
        __syncthreads();

        #pragma unroll 8
        for (int k = 0; k < BK; k++) {
            float4 a0 = *(const float4*)&As[k][ty * 8];
            float4 a1 = *(const float4*)&As[k][ty * 8 + 4];
            float4 bv = *(const float4*)&Bs[k][tx * 4];
            float av[8] = {a0.x, a0.y, a0.z, a0.w, a1.x, a1.y, a1.z, a1.w};
            float bb[4] = {bv.x, bv.y, bv.z, bv.w};
            #pragma unroll
            for (int i = 0; i < 8; i++)
                #pragma unroll
                for (int j = 0; j < 4; j++)
                    acc[i][j] += av[i] * bb[j];
        }
        __syncthreads();
    }

    float4 bi = *(const float4*)&b_ih[n0 + tx * 4];
    float4 bh = *(const float4*)&b_hh[n0 + tx * 4];
    float bsum[4] = {bi.x + bh.x, bi.y + bh.y, bi.z + bh.z, bi.w + bh.w};

    #pragma unroll
    for (int i = 0; i < 8; i++) {
        float4 o;
        o.x = acc[i][0] + bsum[0];
        o.y = acc[i][1] + bsum[1];
        o.z = acc[i][2] + bsum[2];
        o.w = acc[i][3] + bsum[3];
        *(float4*)(out + (long)(m0 + ty * 8 + i) * HID + n0 + tx * 4) = o;
    }
}

// ---------------------------------------------------------------------------
// Kernel B: persistent recurrent kernel.
// 256 blocks (<= 256 CUs -> all co-resident), 256 threads.
// Block owns a 16-batch x 16-column tile of h. W_hh rows staged in LDS (64KB),
// XOR-swizzled so the 16-row ds_read_b128 pattern is conflict-free.
// Software grid barrier: monotonic counter, agent-scope atomics.
// ---------------------------------------------------------------------------
__global__ __launch_bounds__(256) void rnn_kernel(
    const float* __restrict__ h0,    // [B][H] initial hidden
    const float* __restrict__ Whh,   // [H][H]
    float* __restrict__ out,         // [T][B][H] xp in -> h out; h_last at T*B*H
    float* __restrict__ hbuf,        // [2][B][H] scratch
    unsigned* __restrict__ counter)  // zeroed via hipMemsetAsync before launch
{
    __shared__ float4 W4[16][256];   // W4[row][k4 ^ (row&7)] swizzle

    const int bid = blockIdx.x;          // 256 blocks: 64 j-tiles x 4 b-tiles
    const int j0 = (bid & 63) * 16;
    const int b0 = (bid >> 6) * 16;
    const int tid = threadIdx.x;
    const int jj = tid & 15;
    const int bb = tid >> 4;

    // stage 16 rows of W_hh (coalesced: k4 = tid)
    #pragma unroll
    for (int i = 0; i < 16; i++) {
        float4 v = *(const float4*)(Whh + (long)(j0 + i) * HID + tid * 4);
        W4[i][tid ^ (i & 7)] = v;
    }
    __syncthreads();

    const int j = j0 + jj;
    const int b = b0 + bb;
    const int sw = jj & 7;
    const float4* __restrict__ Wrow = &W4[jj][0];
    const unsigned nb = gridDim.x;
    const size_t BH = (size_t)BATCH * HID;

    for (int t = 0; t < T_STEPS; t++) {
        const float4* h4 = (t == 0)
            ? (const float4*)h0
            : (const float4*)(hbuf + ((size_t)((t + 1) & 1)) * BH);
        const float4* __restrict__ hrow = h4 + (size_t)b * (HID / 4);

        float a0 = 0.f, a1 = 0.f, a2 = 0.f, a3 = 0.f;
        #pragma unroll 8
        for (int k4 = 0; k4 < HID / 4; k4++) {
            float4 hv = hrow[k4];
            float4 wv = Wrow[k4 ^ sw];
            a0 += hv.x * wv.x;
            a1 += hv.y * wv.y;
            a2 += hv.z * wv.z;
            a3 += hv.w * wv.w;
        }
        float dot = (a0 + a1) + (a2 + a3);

        size_t oidx = (size_t)t * BH + (size_t)b * HID + j;
        float hn = tanhf(out[oidx] + dot);
        out[oidx] = hn;
        hbuf[((size_t)(t & 1)) * BH + (size_t)b * HID + j] = hn;
        if (t == T_STEPS - 1)
            out[(size_t)T_STEPS * BH + (size_t)b * HID + j] = hn;

        // ---- grid barrier (monotonic, no reset) ----
        __syncthreads();   // compiler drains vmcnt before s_barrier
        if (tid == 0) {
            __hip_atomic_fetch_add(counter, 1u, __ATOMIC_ACQ_REL,
                                   __HIP_MEMORY_SCOPE_AGENT);
            const unsigned target = (unsigned)(t + 1) * nb;
            while (__hip_atomic_load(counter, __ATOMIC_ACQUIRE,
                                     __HIP_MEMORY_SCOPE_AGENT) < target) {
                __builtin_amdgcn_s_sleep(2);
            }
        }
        __syncthreads();
        __threadfence();   // acquire-side invalidate for upcoming h reads
    }
}

// ---------------------------------------------------------------------------
extern "C" void kernel_launch(void* const* d_in, const int* in_sizes, int n_in,
                              void* d_out, int out_size, void* d_ws, size_t ws_size,
                              hipStream_t stream)
{
    const float* input  = (const float*)d_in[0];  // [T,B,I]
    const float* hidden = (const float*)d_in[1];  // [B,H]
    const float* W_ih   = (const float*)d_in[2];  // [H,I]
    const float* W_hh   = (const float*)d_in[3];  // [H,H]
    const float* b_ih   = (const float*)d_in[4];  // [H]
    const float* b_hh   = (const float*)d_in[5];  // [H]
    float* out = (float*)d_out;

    float* hbuf = (float*)d_ws;                                  // 2*B*H floats
    unsigned* counter = (unsigned*)((char*)d_ws +
                        (size_t)2 * BATCH * HID * sizeof(float));

    hipMemsetAsync(counter, 0, sizeof(unsigned), stream);

    dim3 gridA(HID / 64, (T_STEPS * BATCH) / 128, 1);  // (16, 256)
    xproj_kernel<<<gridA, 256, 0, stream>>>(input, W_ih, b_ih, b_hh, out);

    rnn_kernel<<<256, 256, 0, stream>>>(hidden, W_hh, out, hbuf, counter);
}

// Round 2
// 14089.577 us; speedup vs baseline: 1.5848x; 1.5848x over previous
//
#include <hip/hip_runtime.h>
#include <hip/hip_bf16.h>
#include <math.h>

#define T_STEPS 512
#define BATCH   64
#define IN_DIM  1024
#define HID     1024
#define BH_SZ   (BATCH * HID)

// ---------------------------------------------------------------------------
// Kernel A: xp[m][n] = sum_k input[m][k]*W_ih[n][k] + b_ih[n] + b_hh[n]
// (unchanged from round 1 — ~0.8 ms, revisit later)
// ---------------------------------------------------------------------------
__global__ __launch_bounds__(256) void xproj_kernel(
    const float* __restrict__ A,
    const float* __restrict__ W,
    const float* __restrict__ b_ih,
    const float* __restrict__ b_hh,
    float* __restrict__ out)
{
    constexpr int BM = 128, BN = 64, BK = 32;
    __shared__ float As[BK][BM + 4];
    __shared__ float Bs[BK][BN + 4];

    const int n0 = blockIdx.x * BN;
    const int m0 = blockIdx.y * BM;
    const int tid = threadIdx.x;
    const int tx = tid & 15;
    const int ty = tid >> 4;

    float acc[8][4] = {};

    for (int k0 = 0; k0 < IN_DIM; k0 += BK) {
        #pragma unroll
        for (int i = 0; i < 4; i++) {
            int f4 = i * 256 + tid;
            int r = f4 >> 3, c4 = f4 & 7;
            float4 v = *(const float4*)(A + (long)(m0 + r) * IN_DIM + k0 + c4 * 4);
            As[c4 * 4 + 0][r] = v.x;
            As[c4 * 4 + 1][r] = v.y;
            As[c4 * 4 + 2][r] = v.z;
            As[c4 * 4 + 3][r] = v.w;
        }
        #pragma unroll
        for (int i = 0; i < 2; i++) {
            int f4 = i * 256 + tid;
            int r = f4 >> 3, c4 = f4 & 7;
            float4 v = *(const float4*)(W + (long)(n0 + r) * IN_DIM + k0 + c4 * 4);
            Bs[c4 * 4 + 0][r] = v.x;
            Bs[c4 * 4 + 1][r] = v.y;
            Bs[c4 * 4 + 2][r] = v.z;
            Bs[c4 * 4 + 3][r] = v.w;
        }
        __syncthreads();

        #pragma unroll 8
        for (int k = 0; k < BK; k++) {
            float4 a0 = *(const float4*)&As[k][ty * 8];
            float4 a1 = *(const float4*)&As[k][ty * 8 + 4];
            float4 bv = *(const float4*)&Bs[k][tx * 4];
            float av[8] = {a0.x, a0.y, a0.z, a0.w, a1.x, a1.y, a1.z, a1.w};
            float bb[4] = {bv.x, bv.y, bv.z, bv.w};
            #pragma unroll
            for (int i = 0; i < 8; i++)
                #pragma unroll
                for (int j = 0; j < 4; j++)
                    acc[i][j] += av[i] * bb[j];
        }
        __syncthreads();
    }

    float4 bi = *(const float4*)&b_ih[n0 + tx * 4];
    float4 bh = *(const float4*)&b_hh[n0 + tx * 4];
    float bsum[4] = {bi.x + bh.x, bi.y + bh.y, bi.z + bh.z, bi.w + bh.w};

    #pragma unroll
    for (int i = 0; i < 8; i++) {
        float4 o;
        o.x = acc[i][0] + bsum[0];
        o.y = acc[i][1] + bsum[1];
        o.z = acc[i][2] + bsum[2];
        o.w = acc[i][3] + bsum[3];
        *(float4*)(out + (long)(m0 + ty * 8 + i) * HID + n0 + tx * 4) = o;
    }
}

// ---------------------------------------------------------------------------
// Kernel B v2: persistent recurrent kernel, throughput-structured.
// 256 blocks x 512 threads (2 waves/SIMD). Block tile: 16 b x 16 j.
// Thread: 4 b x 4 j x 64 k (k4 strided by 32 across 32 k-chunks).
// W tile (64KB) + h tile (64KB, restaged per step) in LDS; partial-sum
// buffer Plds[32][264] aliased over Hlds. Flag-array grid barrier.
// ---------------------------------------------------------------------------
__global__ __launch_bounds__(512, 2) void rnn_kernel(
    const float* __restrict__ h0,    // [B][H]
    const float* __restrict__ Whh,   // [H][H]
    float* __restrict__ out,         // [T][B][H] xp in -> h out; h_last at end
    unsigned* flags)                 // [256*32], zeroed before launch
{
    __shared__ float Wlds[16][1028];
    __shared__ float Hlds[16][1028];
    float* Plds = &Hlds[0][0];       // [32][264] floats, aliased (phase-safe)

    const int bid = blockIdx.x;      // 64 j-tiles x 4 b-tiles
    const int j0 = (bid & 63) * 16;
    const int b0 = (bid >> 6) * 16;
    const int tid = threadIdx.x;
    const int kc = tid >> 4;         // 0..31   k-chunk (strided)
    const int bt = (tid >> 2) & 3;   // 0..3    b-quad
    const int jt = tid & 3;          // 0..3    j-quad

    // stage W once (rows j0..j0+15)
    #pragma unroll
    for (int i = 0; i < 8; i++) {
        int e = i * 512 + tid;
        int r = e >> 8, c4 = e & 255;
        *(float4*)&Wlds[r][c4 * 4] =
            *(const float4*)(Whh + (size_t)(j0 + r) * HID + c4 * 4);
    }

    const int o = tid;  // output id for tid<256: b-in-tile = o>>4, j-in-tile = o&15
    const size_t out_off = (size_t)(b0 + (o >> 4)) * HID + (size_t)(j0 + (o & 15));

    for (int t = 0; t < T_STEPS; t++) {
        // early xp load (needed only at reduce time -> latency hidden)
        float xp = 0.f;
        if (tid < 256) xp = out[(size_t)t * BH_SZ + out_off];

        // stage h_{t-1} tile: rows b0..b0+15
        const float* hsrc = (t == 0) ? h0 : out + (size_t)(t - 1) * BH_SZ;
        float4 hst[8];
        #pragma unroll
        for (int i = 0; i < 8; i++) {
            int e = i * 512 + tid;
            int r = e >> 8, c4 = e & 255;
            hst[i] = *(const float4*)(hsrc + (size_t)(b0 + r) * HID + c4 * 4);
        }
        #pragma unroll
        for (int i = 0; i < 8; i++) {
            int e = i * 512 + tid;
            int r = e >> 8, c4 = e & 255;
            *(float4*)&Hlds[r][c4 * 4] = hst[i];
        }
        __syncthreads();

        // dot phase: acc[rb][rj] += h[bt*4+rb][k] * W[jt*4+rj][k], k in kc-chunk
        float acc[4][4] = {{0.f}};
        const float4* Hr0 = (const float4*)&Hlds[bt * 4 + 0][0] + kc;
        const float4* Hr1 = (const float4*)&Hlds[bt * 4 + 1][0] + kc;
        const float4* Hr2 = (const float4*)&Hlds[bt * 4 + 2][0] + kc;
        const float4* Hr3 = (const float4*)&Hlds[bt * 4 + 3][0] + kc;
        const float4* Wr0 = (const float4*)&Wlds[jt * 4 + 0][0] + kc;
        const float4* Wr1 = (const float4*)&Wlds[jt * 4 + 1][0] + kc;
        const float4* Wr2 = (const float4*)&Wlds[jt * 4 + 2][0] + kc;
        const float4* Wr3 = (const float4*)&Wlds[jt * 4 + 3][0] + kc;
        #pragma unroll
        for (int i = 0; i < 8; i++) {
            float4 hv[4] = {Hr0[32 * i], Hr1[32 * i], Hr2[32 * i], Hr3[32 * i]};
            float4 wv[4] = {Wr0[32 * i], Wr1[32 * i], Wr2[32 * i], Wr3[32 * i]};
            #pragma unroll
            for (int rb = 0; rb < 4; rb++)
                #pragma unroll
                for (int rj = 0; rj < 4; rj++) {
                    acc[rb][rj] += hv[rb].x * wv[rj].x;
                    acc[rb][rj] += hv[rb].y * wv[rj].y;
                    acc[rb][rj] += hv[rb].z * wv[rj].z;
                    acc[rb][rj] += hv[rb].w * wv[rj].w;
                }
        }
        __syncthreads();   // Hlds reads complete before Plds (alias) writes

        // partials: Plds[kc][o] with o = (bt*4+rb)*16 + jt*4 + rj
        {
            float* Prow = Plds + (size_t)kc * 264;
            #pragma unroll
            for (int rb = 0; rb < 4; rb++) {
                float4 pv = make_float4(acc[rb][0], acc[rb][1], acc[rb][2], acc[rb][3]);
                *(float4*)&Prow[bt * 64 + rb * 16 + jt * 4] = pv;
            }
        }
        __syncthreads();

        // reduce + activation + store
        if (tid < 256) {
            float s = xp;
            #pragma unroll
            for (int k = 0; k < 32; k++) s += Plds[k * 264 + o];
            float hn = tanhf(s);
            out[(size_t)t * BH_SZ + out_off] = hn;
            if (t == T_STEPS - 1)
                out[(size_t)T_STEPS * BH_SZ + out_off] = hn;
        }
        __syncthreads();   // stores drained (per-thread vmcnt) before arrive

        // ---- grid barrier: flag-array, wave-parallel poll ----
        if (tid == 0) {
            __builtin_amdgcn_fence(__ATOMIC_RELEASE, "agent");
            __hip_atomic_store(&flags[bid * 32], (unsigned)(t + 1),
                               __ATOMIC_RELAXED, __HIP_MEMORY_SCOPE_AGENT);
        }
        if (tid < 64) {
            const unsigned target = (unsigned)(t + 1);
            for (;;) {
                int ok = 1;
                #pragma unroll
                for (int g = 0; g < 4; g++) {
                    unsigned v = __hip_atomic_load(&flags[(tid + g * 64) * 32],
                                                   __ATOMIC_ACQUIRE,
                                                   __HIP_MEMORY_SCOPE_AGENT);
                    ok &= (v >= target) ? 1 : 0;
                }
                if (__all(ok)) break;
                __builtin_amdgcn_s_sleep(4);
            }
            __builtin_amdgcn_fence(__ATOMIC_ACQUIRE, "agent");  // L1 inv for fresh h/xp
        }
        __syncthreads();
    }
}

// ---------------------------------------------------------------------------
extern "C" void kernel_launch(void* const* d_in, const int* in_sizes, int n_in,
                              void* d_out, int out_size, void* d_ws, size_t ws_size,
                              hipStream_t stream)
{
    const float* input  = (const float*)d_in[0];  // [T,B,I]
    const float* hidden = (const float*)d_in[1];  // [B,H]
    const float* W_ih   = (const float*)d_in[2];  // [H,I]
    const float* W_hh   = (const float*)d_in[3];  // [H,H]
    const float* b_ih   = (const float*)d_in[4];  // [H]
    const float* b_hh   = (const float*)d_in[5];  // [H]
    float* out = (float*)d_out;

    unsigned* flags = (unsigned*)d_ws;            // 256 blocks * 32 u32 = 32KB
    hipMemsetAsync(flags, 0, 256 * 32 * sizeof(unsigned), stream);

    dim3 gridA(HID / 64, (T_STEPS * BATCH) / 128, 1);
    xproj_kernel<<<gridA, 256, 0, stream>>>(input, W_ih, b_ih, b_hh, out);

    rnn_kernel<<<256, 512, 0, stream>>>(hidden, W_hh, out, flags);
}

// Round 3
// 4625.671 us; speedup vs baseline: 4.8271x; 3.0460x over previous
//
#include <hip/hip_runtime.h>
#include <hip/hip_bf16.h>
#include <math.h>

#define T_STEPS 512
#define BATCH   64
#define IN_DIM  1024
#define HID     1024
#define BH_SZ   (BATCH * HID)

// ---- coherent (agent-scope, L1/L2-bypassing) scalar accessors ------------
__device__ __forceinline__ unsigned ld_coh_u32(const unsigned* p) {
    return __hip_atomic_load(p, __ATOMIC_RELAXED, __HIP_MEMORY_SCOPE_AGENT);
}
__device__ __forceinline__ void st_coh_u32(unsigned* p, unsigned v) {
    __hip_atomic_store(p, v, __ATOMIC_RELAXED, __HIP_MEMORY_SCOPE_AGENT);
}
__device__ __forceinline__ float ld_coh_f32(const float* p) {
    unsigned u = __hip_atomic_load((const unsigned*)p, __ATOMIC_RELAXED,
                                   __HIP_MEMORY_SCOPE_AGENT);
    return __builtin_bit_cast(float, u);
}
__device__ __forceinline__ void st_coh_f32(float* p, float v) {
    __hip_atomic_store((unsigned*)p, __builtin_bit_cast(unsigned, v),
                       __ATOMIC_RELAXED, __HIP_MEMORY_SCOPE_AGENT);
}

// ---------------------------------------------------------------------------
// Kernel A: xp[m][n] = sum_k input[m][k]*W_ih[n][k] + b_ih[n] + b_hh[n]
// (unchanged; ~0.6 ms in clean runs)
// ---------------------------------------------------------------------------
__global__ __launch_bounds__(256) void xproj_kernel(
    const float* __restrict__ A,
    const float* __restrict__ W,
    const float* __restrict__ b_ih,
    const float* __restrict__ b_hh,
    float* __restrict__ out)
{
    constexpr int BM = 128, BN = 64, BK = 32;
    __shared__ float As[BK][BM + 4];
    __shared__ float Bs[BK][BN + 4];

    const int n0 = blockIdx.x * BN;
    const int m0 = blockIdx.y * BM;
    const int tid = threadIdx.x;
    const int tx = tid & 15;
    const int ty = tid >> 4;

    float acc[8][4] = {};

    for (int k0 = 0; k0 < IN_DIM; k0 += BK) {
        #pragma unroll
        for (int i = 0; i < 4; i++) {
            int f4 = i * 256 + tid;
            int r = f4 >> 3, c4 = f4 & 7;
            float4 v = *(const float4*)(A + (long)(m0 + r) * IN_DIM + k0 + c4 * 4);
            As[c4 * 4 + 0][r] = v.x;
            As[c4 * 4 + 1][r] = v.y;
            As[c4 * 4 + 2][r] = v.z;
            As[c4 * 4 + 3][r] = v.w;
        }
        #pragma unroll
        for (int i = 0; i < 2; i++) {
            int f4 = i * 256 + tid;
            int r = f4 >> 3, c4 = f4 & 7;
            float4 v = *(const float4*)(W + (long)(n0 + r) * IN_DIM + k0 + c4 * 4);
            Bs[c4 * 4 + 0][r] = v.x;
            Bs[c4 * 4 + 1][r] = v.y;
            Bs[c4 * 4 + 2][r] = v.z;
            Bs[c4 * 4 + 3][r] = v.w;
        }
        __syncthreads();

        #pragma unroll 8
        for (int k = 0; k < BK; k++) {
            float4 a0 = *(const float4*)&As[k][ty * 8];
            float4 a1 = *(const float4*)&As[k][ty * 8 + 4];
            float4 bv = *(const float4*)&Bs[k][tx * 4];
            float av[8] = {a0.x, a0.y, a0.z, a0.w, a1.x, a1.y, a1.z, a1.w};
            float bb[4] = {bv.x, bv.y, bv.z, bv.w};
            #pragma unroll
            for (int i = 0; i < 8; i++)
                #pragma unroll
                for (int j = 0; j < 4; j++)
                    acc[i][j] += av[i] * bb[j];
        }
        __syncthreads();
    }

    float4 bi = *(const float4*)&b_ih[n0 + tx * 4];
    float4 bh = *(const float4*)&b_hh[n0 + tx * 4];
    float bsum[4] = {bi.x + bh.x, bi.y + bh.y, bi.z + bh.z, bi.w + bh.w};

    #pragma unroll
    for (int i = 0; i < 8; i++) {
        float4 o;
        o.x = acc[i][0] + bsum[0];
        o.y = acc[i][1] + bsum[1];
        o.z = acc[i][2] + bsum[2];
        o.w = acc[i][3] + bsum[3];
        *(float4*)(out + (long)(m0 + ty * 8 + i) * HID + n0 + tx * 4) = o;
    }
}

// ---------------------------------------------------------------------------
// Kernel B v3: persistent recurrent kernel, fence-free coherent h exchange.
// 256 blocks x 512 threads, block tile 16b x 16j, thread tile 4b x 4j x 64k.
// h_t exchanged via hcomm[2][B][H] with relaxed agent-scope (IF-coherent)
// dword accesses — no release/acquire fences, no L2 wb/inv, L2 stays warm
// for the xp stream. Flag-array barrier; xp[t+1] prefetched under the poll.
// ---------------------------------------------------------------------------
__global__ __launch_bounds__(512, 2) void rnn_kernel(
    const float* __restrict__ h0,    // [B][H]
    const float* __restrict__ Whh,   // [H][H]
    float* __restrict__ out,         // [T][B][H] xp in -> h out; h_last at end
    float* hcomm,                    // [2][B][H] coherent h exchange
    unsigned* flags)                 // [256*32], zeroed before launch
{
    __shared__ float Wlds[16][1028];
    __shared__ float Hlds[16][1028];
    float* Plds = &Hlds[0][0];       // [32][264] floats, aliased (phase-safe)

    const int bid = blockIdx.x;      // 64 j-tiles x 4 b-tiles
    const int j0 = (bid & 63) * 16;
    const int b0 = (bid >> 6) * 16;
    const int tid = threadIdx.x;
    const int kc = tid >> 4;         // 0..31 k-chunk
    const int bt = (tid >> 2) & 3;   // 0..3  b-quad
    const int jt = tid & 3;          // 0..3  j-quad

    // stage W once (rows j0..j0+15)
    #pragma unroll
    for (int i = 0; i < 8; i++) {
        int e = i * 512 + tid;
        int r = e >> 8, c4 = e & 255;
        *(float4*)&Wlds[r][c4 * 4] =
            *(const float4*)(Whh + (size_t)(j0 + r) * HID + c4 * 4);
    }

    const int o = tid;               // tid<256: b-in-tile = o>>4, j-in-tile = o&15
    const size_t out_off = (size_t)(b0 + (o >> 4)) * HID + (size_t)(j0 + (o & 15));

    float xp_cur = (tid < 256) ? out[out_off] : 0.f;   // xp for t=0

    for (int t = 0; t < T_STEPS; t++) {
        // ---- stage h_{t-1} tile (rows b0..b0+15) into Hlds ----
        if (t == 0) {
            #pragma unroll
            for (int i = 0; i < 8; i++) {
                int e = i * 512 + tid;
                int r = e >> 8, c4 = e & 255;
                float4 v = *(const float4*)(h0 + (size_t)(b0 + r) * HID + c4 * 4);
                *(float4*)&Hlds[r][c4 * 4] = v;
            }
        } else {
            const float* hsrc = hcomm + (size_t)((t + 1) & 1) * BH_SZ;
            float4 hv[8];
            #pragma unroll
            for (int i = 0; i < 8; i++) {
                int e = i * 512 + tid;
                int r = e >> 8, c4 = e & 255;
                const float* p = hsrc + (size_t)(b0 + r) * HID + c4 * 4;
                hv[i].x = ld_coh_f32(p + 0);
                hv[i].y = ld_coh_f32(p + 1);
                hv[i].z = ld_coh_f32(p + 2);
                hv[i].w = ld_coh_f32(p + 3);
            }
            #pragma unroll
            for (int i = 0; i < 8; i++) {
                int e = i * 512 + tid;
                int r = e >> 8, c4 = e & 255;
                *(float4*)&Hlds[r][c4 * 4] = hv[i];
            }
        }
        __syncthreads();

        // ---- dot phase ----
        float acc[4][4] = {{0.f}};
        const float4* Hr0 = (const float4*)&Hlds[bt * 4 + 0][0] + kc;
        const float4* Hr1 = (const float4*)&Hlds[bt * 4 + 1][0] + kc;
        const float4* Hr2 = (const float4*)&Hlds[bt * 4 + 2][0] + kc;
        const float4* Hr3 = (const float4*)&Hlds[bt * 4 + 3][0] + kc;
        const float4* Wr0 = (const float4*)&Wlds[jt * 4 + 0][0] + kc;
        const float4* Wr1 = (const float4*)&Wlds[jt * 4 + 1][0] + kc;
        const float4* Wr2 = (const float4*)&Wlds[jt * 4 + 2][0] + kc;
        const float4* Wr3 = (const float4*)&Wlds[jt * 4 + 3][0] + kc;
        #pragma unroll
        for (int i = 0; i < 8; i++) {
            float4 hv[4] = {Hr0[32 * i], Hr1[32 * i], Hr2[32 * i], Hr3[32 * i]};
            float4 wv[4] = {Wr0[32 * i], Wr1[32 * i], Wr2[32 * i], Wr3[32 * i]};
            #pragma unroll
            for (int rb = 0; rb < 4; rb++)
                #pragma unroll
                for (int rj = 0; rj < 4; rj++) {
                    acc[rb][rj] += hv[rb].x * wv[rj].x;
                    acc[rb][rj] += hv[rb].y * wv[rj].y;
                    acc[rb][rj] += hv[rb].z * wv[rj].z;
                    acc[rb][rj] += hv[rb].w * wv[rj].w;
                }
        }
        __syncthreads();   // Hlds reads done before Plds (alias) writes

        // ---- partial sums ----
        {
            float* Prow = Plds + (size_t)kc * 264;
            #pragma unroll
            for (int rb = 0; rb < 4; rb++) {
                float4 pv = make_float4(acc[rb][0], acc[rb][1], acc[rb][2], acc[rb][3]);
                *(float4*)&Prow[bt * 64 + rb * 16 + jt * 4] = pv;
            }
        }
        __syncthreads();

        // ---- reduce + tanh + store ----
        if (tid < 256) {
            float s = xp_cur;
            #pragma unroll
            for (int k = 0; k < 32; k++) s += Plds[k * 264 + o];
            float hn = tanhf(s);
            out[(size_t)t * BH_SZ + out_off] = hn;                    // cached
            st_coh_f32(hcomm + (size_t)(t & 1) * BH_SZ + out_off, hn); // coherent
            if (t == T_STEPS - 1)
                out[(size_t)T_STEPS * BH_SZ + out_off] = hn;
        }
        __syncthreads();   // every thread's vmcnt drained -> h globally visible

        // ---- arrive ----
        if (tid == 0) st_coh_u32(&flags[bid * 32], (unsigned)(t + 1));

        // prefetch next xp under the poll (own cell, no other writer)
        float xp_next = 0.f;
        if (tid < 256 && t + 1 < T_STEPS)
            xp_next = out[(size_t)(t + 1) * BH_SZ + out_off];

        // ---- wait ----
        if (tid < 64) {
            const unsigned target = (unsigned)(t + 1);
            for (;;) {
                int ok = 1;
                #pragma unroll
                for (int g = 0; g < 4; g++) {
                    unsigned v = ld_coh_u32(&flags[(tid + g * 64) * 32]);
                    ok &= (v >= target) ? 1 : 0;
                }
                if (__all(ok)) break;
                __builtin_amdgcn_s_sleep(1);
            }
        }
        __syncthreads();
        xp_cur = xp_next;
    }
}

// ---------------------------------------------------------------------------
extern "C" void kernel_launch(void* const* d_in, const int* in_sizes, int n_in,
                              void* d_out, int out_size, void* d_ws, size_t ws_size,
                              hipStream_t stream)
{
    const float* input  = (const float*)d_in[0];
    const float* hidden = (const float*)d_in[1];
    const float* W_ih   = (const float*)d_in[2];
    const float* W_hh   = (const float*)d_in[3];
    const float* b_ih   = (const float*)d_in[4];
    const float* b_hh   = (const float*)d_in[5];
    float* out = (float*)d_out;

    unsigned* flags = (unsigned*)d_ws;                         // 32 KB
    float* hcomm = (float*)((char*)d_ws + 256 * 32 * sizeof(unsigned));
    hipMemsetAsync(flags, 0, 256 * 32 * sizeof(unsigned), stream);

    dim3 gridA(HID / 64, (T_STEPS * BATCH) / 128, 1);
    xproj_kernel<<<gridA, 256, 0, stream>>>(input, W_ih, b_ih, b_hh, out);

    rnn_kernel<<<256, 512, 0, stream>>>(hidden, W_hh, out, hcomm, flags);
}